// Round 1
// baseline (1608.031 us; speedup 1.0000x reference)
//
#include <hip/hip_runtime.h>
#include <hip/hip_bf16.h>

#define D_IN 128
#define D_H 256
#define NEG_SLOPE 0.01f
#define BN_EPS 1e-5f

// ---------------- CSR build ----------------

__global__ void k_count(const int* __restrict__ ei, int* __restrict__ cnt, int E) {
    int e = blockIdx.x * blockDim.x + threadIdx.x;
    if (e < E) atomicAdd(&cnt[ei[E + e]], 1);   // dst = ei[1][e]
}

__global__ void k_deg(const int* __restrict__ cnt, float* __restrict__ dinv,
                      float* __restrict__ self_norm, int N) {
    int n = blockIdx.x * blockDim.x + threadIdx.x;
    if (n < N) {
        float deg = (float)(cnt[n] + 1);
        dinv[n] = rsqrtf(deg);
        self_norm[n] = 1.0f / deg;
    }
}

// exclusive scan of cnt[0..n) into row_ptr[0..n], row_ptr[n]=total. Single block 1024 threads.
__global__ void k_scan(const int* __restrict__ cnt, int* __restrict__ row_ptr, int n) {
    __shared__ int wsum[16];
    __shared__ int carry_s;
    int tid = threadIdx.x;
    int lane = tid & 63, wid = tid >> 6;
    if (tid == 0) carry_s = 0;
    __syncthreads();
    for (int base = 0; base < n; base += 1024) {
        int i = base + tid;
        int v = (i < n) ? cnt[i] : 0;
        // wave inclusive scan
        int x = v;
        #pragma unroll
        for (int off = 1; off < 64; off <<= 1) {
            int t = __shfl_up(x, off, 64);
            if (lane >= off) x += t;
        }
        if (lane == 63) wsum[wid] = x;
        __syncthreads();
        if (wid == 0 && lane < 16) {
            int s = wsum[lane];
            #pragma unroll
            for (int off = 1; off < 16; off <<= 1) {
                int t = __shfl_up(s, off, 16);
                if ((lane & 15) >= off) s += t;
            }
            wsum[lane] = s;
        }
        __syncthreads();
        int woff = (wid == 0) ? 0 : wsum[wid - 1];
        int incl = x + woff;
        if (i < n) row_ptr[i] = carry_s + incl - v;
        __syncthreads();             // everyone has read carry_s
        if (tid == 0) carry_s += wsum[15];
        __syncthreads();
    }
    if (tid == 0) row_ptr[n] = carry_s;
}

__global__ void k_fill(const int* __restrict__ ei, const int* __restrict__ row_ptr,
                       int* __restrict__ fill, const float* __restrict__ dinv,
                       int* __restrict__ csr_src, float* __restrict__ csr_norm, int E) {
    int e = blockIdx.x * blockDim.x + threadIdx.x;
    if (e < E) {
        int src = ei[e];
        int dst = ei[E + e];
        int pos = atomicAdd(&fill[dst], 1);
        int j = row_ptr[dst] + pos;
        csr_src[j] = src;
        csr_norm[j] = dinv[src] * dinv[dst];
    }
}

__global__ void k_init_affine(float* __restrict__ s, float* __restrict__ sh) {
    int c = threadIdx.x;
    s[c] = 1.0f;
    sh[c] = 0.0f;
}

// ---------------- aggregation (pre-GEMM, with lazy BN affine of previous layer) ----------------
// t[n][c] = self_norm[n]*aff(h[n][c]) + sum_{e in in(n)} norm_e * aff(h[src_e][c])
__global__ void k_agg(const float* __restrict__ h, const float* __restrict__ s,
                      const float* __restrict__ sh, const int* __restrict__ row_ptr,
                      const int* __restrict__ csr_src, const float* __restrict__ csr_norm,
                      const float* __restrict__ self_norm, float* __restrict__ t, int di) {
    int n = blockIdx.x;
    int c = threadIdx.x;
    float sc = s[c], shc = sh[c];
    int b = row_ptr[n], e = row_ptr[n + 1];
    float acc = self_norm[n] * (sc * h[(size_t)n * di + c] + shc);
    for (int j = b; j < e; ++j) {
        int src = csr_src[j];
        float w = csr_norm[j];
        acc += w * (sc * h[(size_t)src * di + c] + shc);
    }
    t[(size_t)n * di + c] = acc;
}

// ---------------- GEMM: H = leaky(A @ W + bias), A:[M,K], W:[K,Nc] ----------------
#define BM 64
#define BN 64
#define BK 16

__global__ __launch_bounds__(256) void k_gemm(const float* __restrict__ A,
                                              const float* __restrict__ W,
                                              const float* __restrict__ bias,
                                              float* __restrict__ H,
                                              int M, int K, int Nc) {
    __shared__ float As[BM][BK + 1];
    __shared__ float Bs[BK][BN + 1];
    int tid = threadIdx.x;
    int tx = tid % 16, ty = tid / 16;
    int rowBase = blockIdx.x * BM;
    int colBase = blockIdx.y * BN;
    float acc[4][4] = {};
    for (int k0 = 0; k0 < K; k0 += BK) {
        {
            int c = tid % 16;
            int r = tid / 16;
            #pragma unroll
            for (int i = 0; i < 4; ++i) {
                int rr = rowBase + r + i * 16;
                As[r + i * 16][c] = (rr < M) ? A[(size_t)rr * K + k0 + c] : 0.f;
            }
        }
        {
            int c = tid % 64;
            int r = tid / 64;
            #pragma unroll
            for (int i = 0; i < 4; ++i) {
                Bs[r + i * 4][c] = W[(size_t)(k0 + r + i * 4) * Nc + colBase + c];
            }
        }
        __syncthreads();
        #pragma unroll
        for (int kk = 0; kk < BK; ++kk) {
            float a[4], bb[4];
            #pragma unroll
            for (int i = 0; i < 4; ++i) a[i] = As[ty * 4 + i][kk];
            #pragma unroll
            for (int j = 0; j < 4; ++j) bb[j] = Bs[kk][tx * 4 + j];
            #pragma unroll
            for (int i = 0; i < 4; ++i)
                #pragma unroll
                for (int j = 0; j < 4; ++j)
                    acc[i][j] += a[i] * bb[j];
        }
        __syncthreads();
    }
    #pragma unroll
    for (int i = 0; i < 4; ++i) {
        int r = rowBase + ty * 4 + i;
        if (r < M) {
            #pragma unroll
            for (int j = 0; j < 4; ++j) {
                int c = colBase + tx * 4 + j;
                float z = acc[i][j] + bias[c];
                z = z > 0.f ? z : NEG_SLOPE * z;
                H[(size_t)r * Nc + c] = z;
            }
        }
    }
}

// ---------------- BN stats ----------------
__global__ void k_stats(const float* __restrict__ h, float* __restrict__ sums,
                        int M, int do_) {
    int c = threadIdx.x;           // blockDim.x == do_
    float s1 = 0.f, s2 = 0.f;
    for (int r = blockIdx.x; r < M; r += gridDim.x) {
        float v = h[(size_t)r * do_ + c];
        s1 += v;
        s2 += v * v;
    }
    atomicAdd(&sums[c], s1);
    atomicAdd(&sums[256 + c], s2);
}

__global__ void k_finalize(const float* __restrict__ sums, const float* __restrict__ g,
                           const float* __restrict__ bt, float* __restrict__ s_out,
                           float* __restrict__ sh_out, float Nf) {
    int c = threadIdx.x;           // blockDim.x == do_
    float mu = sums[c] / Nf;
    float var = sums[256 + c] / Nf - mu * mu;
    float rs = rsqrtf(var + BN_EPS);
    float sc = g[c] * rs;
    s_out[c] = sc;
    sh_out[c] = bt[c] - mu * sc;
}

// ---------------- global mean pool (batch sorted) ----------------
__global__ void k_pool(const float* __restrict__ h, const float* __restrict__ s,
                       const float* __restrict__ sh, const int* __restrict__ batch,
                       float* __restrict__ out, int N, int G) {
    int g = blockIdx.x;
    int c = threadIdx.x;           // 128
    // lower_bound(batch, g) and lower_bound(batch, g+1)
    int lo = 0, hi = N;
    while (lo < hi) { int mid = (lo + hi) >> 1; if (batch[mid] < g) lo = mid + 1; else hi = mid; }
    int start = lo;
    hi = N;
    while (lo < hi) { int mid = (lo + hi) >> 1; if (batch[mid] < g + 1) lo = mid + 1; else hi = mid; }
    int end = lo;
    float sc = s[c], shc = sh[c];
    float acc = 0.f;
    for (int r = start; r < end; ++r)
        acc += sc * h[(size_t)r * 128 + c] + shc;
    int cnt = end - start;
    out[(size_t)g * 128 + c] = acc / (float)max(cnt, 1);
}

// ---------------- host ----------------

static inline size_t align256(size_t x) { return (x + 255) & ~(size_t)255; }

extern "C" void kernel_launch(void* const* d_in, const int* in_sizes, int n_in,
                              void* d_out, int out_size, void* d_ws, size_t ws_size,
                              hipStream_t stream) {
    const float* x   = (const float*)d_in[0];
    const int* ei    = (const int*)d_in[1];
    const int* batch = (const int*)d_in[2];
    const float* Wp[4]  = {(const float*)d_in[3], (const float*)d_in[7],
                           (const float*)d_in[11], (const float*)d_in[15]};
    const float* bp[4]  = {(const float*)d_in[4], (const float*)d_in[8],
                           (const float*)d_in[12], (const float*)d_in[16]};
    const float* gp[4]  = {(const float*)d_in[5], (const float*)d_in[9],
                           (const float*)d_in[13], (const float*)d_in[17]};
    const float* btp[4] = {(const float*)d_in[6], (const float*)d_in[10],
                           (const float*)d_in[14], (const float*)d_in[18]};

    const int N = in_sizes[0] / D_IN;
    const int E = in_sizes[1] / 2;
    const int G = out_size / 128;

    // workspace layout
    char* p = (char*)d_ws;
    int* deg_cnt = (int*)p;            p += align256((size_t)N * 4);       // reused as fill counter
    int* row_ptr = (int*)p;            p += align256((size_t)(N + 1) * 4);
    float* dinv = (float*)p;           p += align256((size_t)N * 4);
    float* self_norm = (float*)p;      p += align256((size_t)N * 4);
    int* csr_src = (int*)p;            p += align256((size_t)E * 4);
    float* csr_norm = (float*)p;       p += align256((size_t)E * 4);
    float* sums = (float*)p;           p += align256(512 * 4);
    float* s_arr = (float*)p;          p += align256(5 * 256 * 4);
    float* sh_arr = (float*)p;         p += align256(5 * 256 * 4);
    float* bufA = (float*)p;           p += align256((size_t)N * D_H * 4); // t (agg output)
    float* bufB = (float*)p;           p += align256((size_t)N * D_H * 4); // h (gemm output)

    // ---- CSR build ----
    hipMemsetAsync(deg_cnt, 0, (size_t)N * 4, stream);
    k_count<<<(E + 255) / 256, 256, 0, stream>>>(ei, deg_cnt, E);
    k_deg<<<(N + 255) / 256, 256, 0, stream>>>(deg_cnt, dinv, self_norm, N);
    k_scan<<<1, 1024, 0, stream>>>(deg_cnt, row_ptr, N);
    hipMemsetAsync(deg_cnt, 0, (size_t)N * 4, stream);
    k_fill<<<(E + 255) / 256, 256, 0, stream>>>(ei, row_ptr, deg_cnt, dinv,
                                                csr_src, csr_norm, E);
    k_init_affine<<<1, 256, 0, stream>>>(s_arr, sh_arr);

    const int din[4]  = {D_IN, D_H, D_H, D_H};
    const int dout[4] = {D_H, D_H, D_H, D_IN};

    const float* hin = x;
    for (int L = 0; L < 4; ++L) {
        int di = din[L], doo = dout[L];
        // t = aggregate(affine(hin))
        k_agg<<<N, di, 0, stream>>>(hin, s_arr + L * 256, sh_arr + L * 256,
                                    row_ptr, csr_src, csr_norm, self_norm, bufA, di);
        // h = leaky(t @ W + b)
        dim3 grid((N + BM - 1) / BM, doo / BN);
        k_gemm<<<grid, 256, 0, stream>>>(bufA, Wp[L], bp[L], bufB, N, di, doo);
        // BN stats -> affine for next consumer
        hipMemsetAsync(sums, 0, 512 * 4, stream);
        k_stats<<<256, doo, 0, stream>>>(bufB, sums, N, doo);
        k_finalize<<<1, doo, 0, stream>>>(sums, gp[L], btp[L],
                                          s_arr + (L + 1) * 256, sh_arr + (L + 1) * 256,
                                          (float)N);
        hin = bufB;
    }

    // pool with layer-4 affine applied lazily
    k_pool<<<G, 128, 0, stream>>>(bufB, s_arr + 4 * 256, sh_arr + 4 * 256,
                                  batch, (float*)d_out, N, G);
}

// Round 2
// 1143.708 us; speedup vs baseline: 1.4060x; 1.4060x over previous
//
#include <hip/hip_runtime.h>
#include <hip/hip_bf16.h>

#define D_IN 128
#define D_H 256
#define NEG_SLOPE 0.01f
#define BN_EPS 1e-5f
#define POOL_S 16

// ---------------- CSR build ----------------

__global__ void k_count(const int* __restrict__ ei, int* __restrict__ cnt, int E) {
    int e = blockIdx.x * blockDim.x + threadIdx.x;
    if (e < E) atomicAdd(&cnt[ei[E + e]], 1);   // dst = ei[1][e]
}

__global__ void k_deg(const int* __restrict__ cnt, float* __restrict__ dinv,
                      float* __restrict__ self_norm, int N) {
    int n = blockIdx.x * blockDim.x + threadIdx.x;
    if (n < N) {
        float deg = (float)(cnt[n] + 1);
        dinv[n] = rsqrtf(deg);
        self_norm[n] = 1.0f / deg;
    }
}

// exclusive scan of cnt[0..n) into row_ptr[0..n], row_ptr[n]=total. Single block 1024 threads.
__global__ void k_scan(const int* __restrict__ cnt, int* __restrict__ row_ptr, int n) {
    __shared__ int wsum[16];
    __shared__ int carry_s;
    int tid = threadIdx.x;
    int lane = tid & 63, wid = tid >> 6;
    if (tid == 0) carry_s = 0;
    __syncthreads();
    for (int base = 0; base < n; base += 1024) {
        int i = base + tid;
        int v = (i < n) ? cnt[i] : 0;
        int x = v;
        #pragma unroll
        for (int off = 1; off < 64; off <<= 1) {
            int t = __shfl_up(x, off, 64);
            if (lane >= off) x += t;
        }
        if (lane == 63) wsum[wid] = x;
        __syncthreads();
        if (wid == 0 && lane < 16) {
            int s = wsum[lane];
            #pragma unroll
            for (int off = 1; off < 16; off <<= 1) {
                int t = __shfl_up(s, off, 16);
                if ((lane & 15) >= off) s += t;
            }
            wsum[lane] = s;
        }
        __syncthreads();
        int woff = (wid == 0) ? 0 : wsum[wid - 1];
        int incl = x + woff;
        if (i < n) row_ptr[i] = carry_s + incl - v;
        __syncthreads();
        if (tid == 0) carry_s += wsum[15];
        __syncthreads();
    }
    if (tid == 0) row_ptr[n] = carry_s;
}

__global__ void k_fill(const int* __restrict__ ei, const int* __restrict__ row_ptr,
                       int* __restrict__ fill, const float* __restrict__ dinv,
                       int* __restrict__ csr_src, float* __restrict__ csr_norm, int E) {
    int e = blockIdx.x * blockDim.x + threadIdx.x;
    if (e < E) {
        int src = ei[e];
        int dst = ei[E + e];
        int pos = atomicAdd(&fill[dst], 1);
        int j = row_ptr[dst] + pos;
        csr_src[j] = src;
        csr_norm[j] = dinv[src] * dinv[dst];
    }
}

__global__ void k_init_affine(float* __restrict__ s, float* __restrict__ sh) {
    int c = threadIdx.x;
    s[c] = 1.0f;
    sh[c] = 0.0f;
}

// ---------------- aggregation ----------------
// t[n][:] = s * ( self_norm[n]*h[n] + sum_e w_e*h[src_e] ) + sh * ( self_norm[n] + sum_e w_e )
// float4 per thread; EP edge-parallel groups; LDS tree reduce.
template<int DI>
__global__ __launch_bounds__(256) void k_agg_v(const float* __restrict__ h,
    const float* __restrict__ s, const float* __restrict__ sh,
    const int* __restrict__ row_ptr, const int* __restrict__ csr_src,
    const float* __restrict__ csr_norm, const float* __restrict__ self_norm,
    float* __restrict__ t) {
    constexpr int COLT = DI / 4;        // threads covering columns (float4 each)
    constexpr int EP = 256 / COLT;      // edge-parallel groups
    int n = blockIdx.x;
    int tid = threadIdx.x;
    int ct = tid % COLT;
    int gp = tid / COLT;
    int b = row_ptr[n], e = row_ptr[n + 1];
    float4 acc = make_float4(0.f, 0.f, 0.f, 0.f);
    float wsum = 0.f;
    for (int j = b + gp; j < e; j += EP) {
        int src = csr_src[j];
        float w = csr_norm[j];
        const float4 hv = *(const float4*)(h + (size_t)src * DI + ct * 4);
        acc.x += w * hv.x; acc.y += w * hv.y; acc.z += w * hv.z; acc.w += w * hv.w;
        wsum += w;
    }
    __shared__ float4 red[256];
    __shared__ float wred[256];
    red[tid] = acc; wred[tid] = wsum;
    __syncthreads();
    #pragma unroll
    for (int st = 128; st >= COLT; st >>= 1) {
        if (tid < st) {
            float4 o = red[tid + st];
            red[tid].x += o.x; red[tid].y += o.y; red[tid].z += o.z; red[tid].w += o.w;
            wred[tid] += wred[tid + st];
        }
        __syncthreads();
    }
    if (tid < COLT) {
        float4 a = red[tid];
        float ws = wred[tid];
        float sn = self_norm[n];
        float4 hv = *(const float4*)(h + (size_t)n * DI + tid * 4);
        float4 sv = *(const float4*)(s + tid * 4);
        float4 shv = *(const float4*)(sh + tid * 4);
        float4 o;
        o.x = sv.x * (a.x + sn * hv.x) + shv.x * (ws + sn);
        o.y = sv.y * (a.y + sn * hv.y) + shv.y * (ws + sn);
        o.z = sv.z * (a.z + sn * hv.z) + shv.z * (ws + sn);
        o.w = sv.w * (a.w + sn * hv.w) + shv.w * (ws + sn);
        *(float4*)(t + (size_t)n * DI + tid * 4) = o;
    }
}

// ---------------- GEMM: H = leaky(A @ W + bias), fused BN-stats partial reduce ----------------
#define BM 128
#define BN 64
#define BK 16

__global__ __launch_bounds__(256) void k_gemm(const float* __restrict__ A,
                                              const float* __restrict__ W,
                                              const float* __restrict__ bias,
                                              float* __restrict__ H,
                                              float* __restrict__ sums,
                                              int M, int K, int Nc) {
    __shared__ float As[BM][BK + 1];
    __shared__ float Bs[BK][BN + 1];
    int tid = threadIdx.x;
    int tx = tid % 16, ty = tid / 16;
    int rowBase = blockIdx.x * BM;
    int colBase = blockIdx.y * BN;
    float acc[8][4] = {};
    for (int k0 = 0; k0 < K; k0 += BK) {
        {
            int c = tid % 16, r = tid / 16;
            #pragma unroll
            for (int i = 0; i < 8; ++i) {
                int rr = rowBase + r + i * 16;
                As[r + i * 16][c] = (rr < M) ? A[(size_t)rr * K + k0 + c] : 0.f;
            }
        }
        {
            int c = tid % 64, r = tid / 64;
            #pragma unroll
            for (int i = 0; i < 4; ++i)
                Bs[r + i * 4][c] = W[(size_t)(k0 + r + i * 4) * Nc + colBase + c];
        }
        __syncthreads();
        #pragma unroll
        for (int kk = 0; kk < BK; ++kk) {
            float a[8], bb[4];
            #pragma unroll
            for (int i = 0; i < 8; ++i) a[i] = As[ty * 8 + i][kk];
            #pragma unroll
            for (int j = 0; j < 4; ++j) bb[j] = Bs[kk][tx * 4 + j];
            #pragma unroll
            for (int i = 0; i < 8; ++i)
                #pragma unroll
                for (int j = 0; j < 4; ++j)
                    acc[i][j] += a[i] * bb[j];
        }
        __syncthreads();
    }
    // epilogue: bias + LeakyReLU + store + per-column partial stats
    float p1[4] = {}, p2[4] = {};
    #pragma unroll
    for (int i = 0; i < 8; ++i) {
        int r = rowBase + ty * 8 + i;
        if (r < M) {
            #pragma unroll
            for (int j = 0; j < 4; ++j) {
                int c = colBase + tx * 4 + j;
                float z = acc[i][j] + bias[c];
                z = z > 0.f ? z : NEG_SLOPE * z;
                H[(size_t)r * Nc + c] = z;
                p1[j] += z;
                p2[j] += z * z;
            }
        }
    }
    __shared__ float r1[16][64];
    __shared__ float r2[16][64];
    #pragma unroll
    for (int j = 0; j < 4; ++j) { r1[ty][tx * 4 + j] = p1[j]; r2[ty][tx * 4 + j] = p2[j]; }
    __syncthreads();
    if (tid < 64) {
        float s1 = 0.f, s2 = 0.f;
        #pragma unroll
        for (int i = 0; i < 16; ++i) { s1 += r1[i][tid]; s2 += r2[i][tid]; }
        atomicAdd(&sums[colBase + tid], s1);
        atomicAdd(&sums[256 + colBase + tid], s2);
    }
}

// ---------------- BN finalize -> affine ----------------
__global__ void k_finalize(const float* __restrict__ sums, const float* __restrict__ g,
                           const float* __restrict__ bt, float* __restrict__ s_out,
                           float* __restrict__ sh_out, float Nf) {
    int c = threadIdx.x;
    float mu = sums[c] / Nf;
    float var = sums[256 + c] / Nf - mu * mu;
    float rs = rsqrtf(var + BN_EPS);
    float sc = g[c] * rs;
    s_out[c] = sc;
    sh_out[c] = bt[c] - mu * sc;
}

// ---------------- global mean pool, two-stage ----------------
__global__ void k_pool1(const float* __restrict__ h, const int* __restrict__ batch,
                        float* __restrict__ part, int N) {
    int g = blockIdx.x;
    int sidx = blockIdx.y;
    int c = threadIdx.x;   // 128
    int lo = 0, hi = N;
    while (lo < hi) { int m = (lo + hi) >> 1; if (batch[m] < g) lo = m + 1; else hi = m; }
    int start = lo; hi = N;
    while (lo < hi) { int m = (lo + hi) >> 1; if (batch[m] < g + 1) lo = m + 1; else hi = m; }
    int end = lo;
    float acc = 0.f;
    for (int r = start + sidx; r < end; r += POOL_S)
        acc += h[(size_t)r * 128 + c];
    part[((size_t)g * POOL_S + sidx) * 128 + c] = acc;
}

__global__ void k_pool2(const float* __restrict__ part, const int* __restrict__ batch,
                        const float* __restrict__ s, const float* __restrict__ sh,
                        float* __restrict__ out, int N) {
    int g = blockIdx.x;
    int c = threadIdx.x;   // 128
    int lo = 0, hi = N;
    while (lo < hi) { int m = (lo + hi) >> 1; if (batch[m] < g) lo = m + 1; else hi = m; }
    int start = lo; hi = N;
    while (lo < hi) { int m = (lo + hi) >> 1; if (batch[m] < g + 1) lo = m + 1; else hi = m; }
    int cnt = lo - start;
    float acc = 0.f;
    #pragma unroll
    for (int i = 0; i < POOL_S; ++i) acc += part[((size_t)g * POOL_S + i) * 128 + c];
    out[(size_t)g * 128 + c] = (cnt > 0) ? (s[c] * acc / (float)cnt + sh[c]) : 0.f;
}

// ---------------- host ----------------

static inline size_t align256(size_t x) { return (x + 255) & ~(size_t)255; }

extern "C" void kernel_launch(void* const* d_in, const int* in_sizes, int n_in,
                              void* d_out, int out_size, void* d_ws, size_t ws_size,
                              hipStream_t stream) {
    const float* x   = (const float*)d_in[0];
    const int* ei    = (const int*)d_in[1];
    const int* batch = (const int*)d_in[2];
    const float* Wp[4]  = {(const float*)d_in[3], (const float*)d_in[7],
                           (const float*)d_in[11], (const float*)d_in[15]};
    const float* bp[4]  = {(const float*)d_in[4], (const float*)d_in[8],
                           (const float*)d_in[12], (const float*)d_in[16]};
    const float* gp[4]  = {(const float*)d_in[5], (const float*)d_in[9],
                           (const float*)d_in[13], (const float*)d_in[17]};
    const float* btp[4] = {(const float*)d_in[6], (const float*)d_in[10],
                           (const float*)d_in[14], (const float*)d_in[18]};

    const int N = in_sizes[0] / D_IN;
    const int E = in_sizes[1] / 2;
    const int G = out_size / 128;

    // workspace layout
    char* p = (char*)d_ws;
    int* deg_cnt = (int*)p;            p += align256((size_t)N * 4);       // reused as fill counter
    int* row_ptr = (int*)p;            p += align256((size_t)(N + 1) * 4);
    float* dinv = (float*)p;           p += align256((size_t)N * 4);
    float* self_norm = (float*)p;      p += align256((size_t)N * 4);
    int* csr_src = (int*)p;            p += align256((size_t)E * 4);
    float* csr_norm = (float*)p;       p += align256((size_t)E * 4);
    float* sums = (float*)p;           p += align256(512 * 4);
    float* s_arr = (float*)p;          p += align256(5 * 256 * 4);
    float* sh_arr = (float*)p;         p += align256(5 * 256 * 4);
    float* part = (float*)p;           p += align256((size_t)G * POOL_S * 128 * 4);
    float* bufA = (float*)p;           p += align256((size_t)N * D_H * 4); // agg output
    float* bufB = (float*)p;           p += align256((size_t)N * D_H * 4); // gemm output

    // ---- CSR build ----
    hipMemsetAsync(deg_cnt, 0, (size_t)N * 4, stream);
    k_count<<<(E + 255) / 256, 256, 0, stream>>>(ei, deg_cnt, E);
    k_deg<<<(N + 255) / 256, 256, 0, stream>>>(deg_cnt, dinv, self_norm, N);
    k_scan<<<1, 1024, 0, stream>>>(deg_cnt, row_ptr, N);
    hipMemsetAsync(deg_cnt, 0, (size_t)N * 4, stream);
    k_fill<<<(E + 255) / 256, 256, 0, stream>>>(ei, row_ptr, deg_cnt, dinv,
                                                csr_src, csr_norm, E);
    k_init_affine<<<1, 256, 0, stream>>>(s_arr, sh_arr);

    const int din[4]  = {D_IN, D_H, D_H, D_H};
    const int dout[4] = {D_H, D_H, D_H, D_IN};

    const float* hin = x;
    for (int L = 0; L < 4; ++L) {
        int di = din[L], doo = dout[L];
        if (di == 128)
            k_agg_v<128><<<N, 256, 0, stream>>>(hin, s_arr + L * 256, sh_arr + L * 256,
                                                row_ptr, csr_src, csr_norm, self_norm, bufA);
        else
            k_agg_v<256><<<N, 256, 0, stream>>>(hin, s_arr + L * 256, sh_arr + L * 256,
                                                row_ptr, csr_src, csr_norm, self_norm, bufA);
        hipMemsetAsync(sums, 0, 512 * 4, stream);
        dim3 grid((N + BM - 1) / BM, doo / BN);
        k_gemm<<<grid, 256, 0, stream>>>(bufA, Wp[L], bp[L], bufB, sums, N, di, doo);
        k_finalize<<<1, doo, 0, stream>>>(sums, gp[L], btp[L],
                                          s_arr + (L + 1) * 256, sh_arr + (L + 1) * 256,
                                          (float)N);
        hin = bufB;
    }

    dim3 pgrid(G, POOL_S);
    k_pool1<<<pgrid, 128, 0, stream>>>(bufB, batch, part, N);
    k_pool2<<<G, 128, 0, stream>>>(part, batch, s_arr + 4 * 256, sh_arr + 4 * 256,
                                   (float*)d_out, N);
}

// Round 3
// 704.359 us; speedup vs baseline: 2.2830x; 1.6238x over previous
//
#include <hip/hip_runtime.h>
#include <hip/hip_bf16.h>

#define NEG_SLOPE 0.01f
#define BN_EPS 1e-5f
#define POOL_S 16

typedef __attribute__((ext_vector_type(8))) short short8;
typedef __attribute__((ext_vector_type(4))) float f32x4;
typedef __attribute__((ext_vector_type(4))) unsigned short ushort4v;

__device__ __forceinline__ float bf2f(unsigned short b) {
    unsigned int u = ((unsigned int)b) << 16;
    float f; __builtin_memcpy(&f, &u, 4); return f;
}
__device__ __forceinline__ unsigned short f2bf(float f) {
    unsigned int u; __builtin_memcpy(&u, &f, 4);
    u = (u + 0x7FFFu + ((u >> 16) & 1u)) >> 16;
    return (unsigned short)u;
}

// ---------------- CSR build ----------------

__global__ void k_count(const int* __restrict__ ei, int* __restrict__ cnt, int E) {
    int e = blockIdx.x * blockDim.x + threadIdx.x;
    if (e < E) atomicAdd(&cnt[ei[E + e]], 1);
}

__global__ void k_deg(const int* __restrict__ cnt, float* __restrict__ dinv,
                      float* __restrict__ self_norm, int N) {
    int n = blockIdx.x * blockDim.x + threadIdx.x;
    if (n < N) {
        float deg = (float)(cnt[n] + 1);
        dinv[n] = rsqrtf(deg);
        self_norm[n] = 1.0f / deg;
    }
}

__global__ void k_scan(const int* __restrict__ cnt, int* __restrict__ row_ptr, int n) {
    __shared__ int wsum[16];
    __shared__ int carry_s;
    int tid = threadIdx.x;
    int lane = tid & 63, wid = tid >> 6;
    if (tid == 0) carry_s = 0;
    __syncthreads();
    for (int base = 0; base < n; base += 1024) {
        int i = base + tid;
        int v = (i < n) ? cnt[i] : 0;
        int x = v;
        #pragma unroll
        for (int off = 1; off < 64; off <<= 1) {
            int t = __shfl_up(x, off, 64);
            if (lane >= off) x += t;
        }
        if (lane == 63) wsum[wid] = x;
        __syncthreads();
        if (wid == 0 && lane < 16) {
            int s = wsum[lane];
            #pragma unroll
            for (int off = 1; off < 16; off <<= 1) {
                int t = __shfl_up(s, off, 16);
                if ((lane & 15) >= off) s += t;
            }
            wsum[lane] = s;
        }
        __syncthreads();
        int woff = (wid == 0) ? 0 : wsum[wid - 1];
        int incl = x + woff;
        if (i < n) row_ptr[i] = carry_s + incl - v;
        __syncthreads();
        if (tid == 0) carry_s += wsum[15];
        __syncthreads();
    }
    if (tid == 0) row_ptr[n] = carry_s;
}

__global__ void k_fill(const int* __restrict__ ei, const int* __restrict__ row_ptr,
                       int* __restrict__ fill, const float* __restrict__ dinv,
                       int* __restrict__ csr_src, float* __restrict__ csr_norm, int E) {
    int e = blockIdx.x * blockDim.x + threadIdx.x;
    if (e < E) {
        int src = ei[e];
        int dst = ei[E + e];
        int pos = atomicAdd(&fill[dst], 1);
        int j = row_ptr[dst] + pos;
        csr_src[j] = src;
        csr_norm[j] = dinv[src] * dinv[dst];
    }
}

__global__ void k_init_affine(float* __restrict__ s, float* __restrict__ sh) {
    int c = threadIdx.x;
    s[c] = 1.0f;
    sh[c] = 0.0f;
}

// ---------------- W transpose + bf16 convert: Wt[n][k] = W[k][n] ----------------
__global__ void k_prepW(const float* __restrict__ W, unsigned short* __restrict__ Wt,
                        int K, int DO) {
    int idx = blockIdx.x * blockDim.x + threadIdx.x;
    if (idx < K * DO) {
        int k = idx / DO, n = idx % DO;
        Wt[(size_t)n * K + k] = f2bf(W[idx]);
    }
}

// ---------------- aggregation (bf16 out, lazy BN affine) ----------------
// t[n][:] = s*(sum_e w_e*h[src_e] + sn*h[n]) + sh*(sum_e w_e + sn)
template<int DI, bool BF16IN>
__global__ __launch_bounds__(256) void k_agg(const void* __restrict__ hv,
    const float* __restrict__ s, const float* __restrict__ sh,
    const int* __restrict__ row_ptr, const int* __restrict__ csr_src,
    const float* __restrict__ csr_norm, const float* __restrict__ self_norm,
    unsigned short* __restrict__ t) {
    constexpr int VEC = BF16IN ? 8 : 4;
    constexpr int COLT = DI / VEC;
    constexpr int EP = 256 / COLT;
    __shared__ float red[VEC][256];
    __shared__ float wred[256];
    int n = blockIdx.x, tid = threadIdx.x;
    int ct = tid % COLT, gp = tid / COLT;
    int b = row_ptr[n], e = row_ptr[n + 1];
    float acc[VEC] = {};
    float wsum = 0.f;
    for (int j = b + gp; j < e; j += EP) {
        int src = csr_src[j];
        float w = csr_norm[j];
        if constexpr (BF16IN) {
            const short8 hvv = *(const short8*)((const unsigned short*)hv + (size_t)src * DI + ct * 8);
            #pragma unroll
            for (int i = 0; i < 8; ++i) acc[i] += w * bf2f((unsigned short)hvv[i]);
        } else {
            const float4 hvv = *(const float4*)((const float*)hv + (size_t)src * DI + ct * 4);
            acc[0] += w * hvv.x; acc[1] += w * hvv.y; acc[2] += w * hvv.z; acc[3] += w * hvv.w;
        }
        wsum += w;
    }
    #pragma unroll
    for (int i = 0; i < VEC; ++i) red[i][tid] = acc[i];
    wred[tid] = wsum;
    __syncthreads();
    for (int st = 128; st >= COLT; st >>= 1) {
        if (tid < st) {
            #pragma unroll
            for (int i = 0; i < VEC; ++i) red[i][tid] += red[i][tid + st];
            wred[tid] += wred[tid + st];
        }
        __syncthreads();
    }
    if (tid < COLT) {
        float sn = self_norm[n];
        float ws = wred[tid] + sn;
        float hs[VEC];
        if constexpr (BF16IN) {
            const short8 hsv = *(const short8*)((const unsigned short*)hv + (size_t)n * DI + tid * 8);
            #pragma unroll
            for (int i = 0; i < 8; ++i) hs[i] = bf2f((unsigned short)hsv[i]);
        } else {
            const float4 hsv = *(const float4*)((const float*)hv + (size_t)n * DI + tid * 4);
            hs[0] = hsv.x; hs[1] = hsv.y; hs[2] = hsv.z; hs[3] = hsv.w;
        }
        if constexpr (VEC == 8) {
            short8 ov;
            #pragma unroll
            for (int i = 0; i < 8; ++i) {
                int col = tid * 8 + i;
                float o = s[col] * (red[i][tid] + sn * hs[i]) + sh[col] * ws;
                ov[i] = (short)f2bf(o);
            }
            *(short8*)(t + (size_t)n * DI + tid * 8) = ov;
        } else {
            ushort4v ov;
            #pragma unroll
            for (int i = 0; i < 4; ++i) {
                int col = tid * 4 + i;
                float o = s[col] * (red[i][tid] + sn * hs[i]) + sh[col] * ws;
                ov[i] = f2bf(o);
            }
            *(ushort4v*)(t + (size_t)n * DI + tid * 4) = ov;
        }
    }
}

// ---------------- MFMA GEMM: H = bf16(leaky(A@W + bias)), fused BN partial sums ---------
// A: [M x K] bf16, Wt: [DO x K] bf16 (W transposed), H: [M x DO] bf16
// Block: 128 rows x DO cols. Waves: 2 row-halves x (DO/32) col-strips, 4x2 16x16 frags each.
template<int K, int DO>
__global__ __launch_bounds__(DO == 256 ? 1024 : 512) void k_mfma(
    const unsigned short* __restrict__ A, const unsigned short* __restrict__ Wt,
    const float* __restrict__ bias, unsigned short* __restrict__ H,
    float* __restrict__ sums, int M) {
    int tid = threadIdx.x;
    int l = tid & 63, w = tid >> 6;
    int wr = w & 1, wc = w >> 1;
    int Rb = blockIdx.x * 128 + wr * 64;
    int cb = wc * 32;
    int rl = l & 15;
    int kl = (l >> 4) * 8;
    f32x4 acc[4][2] = {};
    for (int k0 = 0; k0 < K; k0 += 32) {
        short8 b0 = *(const short8*)(Wt + (size_t)(cb + rl) * K + k0 + kl);
        short8 b1 = *(const short8*)(Wt + (size_t)(cb + 16 + rl) * K + k0 + kl);
        #pragma unroll
        for (int mf = 0; mf < 4; ++mf) {
            int row = Rb + mf * 16 + rl;
            if (row >= M) row = M - 1;
            short8 a = *(const short8*)(A + (size_t)row * K + k0 + kl);
            acc[mf][0] = __builtin_amdgcn_mfma_f32_16x16x32_bf16(a, b0, acc[mf][0], 0, 0, 0);
            acc[mf][1] = __builtin_amdgcn_mfma_f32_16x16x32_bf16(a, b1, acc[mf][1], 0, 0, 0);
        }
    }
    __shared__ float ls[2][DO];
    for (int c = tid; c < DO; c += blockDim.x) { ls[0][c] = 0.f; ls[1][c] = 0.f; }
    __syncthreads();
    #pragma unroll
    for (int nf = 0; nf < 2; ++nf) {
        int col = cb + nf * 16 + rl;
        float bcol = bias[col];
        float p1 = 0.f, p2 = 0.f;
        #pragma unroll
        for (int mf = 0; mf < 4; ++mf) {
            #pragma unroll
            for (int r = 0; r < 4; ++r) {
                int row = Rb + mf * 16 + (l >> 4) * 4 + r;
                if (row < M) {
                    float z = acc[mf][nf][r] + bcol;
                    z = z > 0.f ? z : NEG_SLOPE * z;
                    H[(size_t)row * DO + col] = f2bf(z);
                    p1 += z; p2 += z * z;
                }
            }
        }
        atomicAdd(&ls[0][col], p1);
        atomicAdd(&ls[1][col], p2);
    }
    __syncthreads();
    for (int c = tid; c < DO; c += blockDim.x) {
        atomicAdd(&sums[c], ls[0][c]);
        atomicAdd(&sums[256 + c], ls[1][c]);
    }
}

// ---------------- BN finalize -> affine ----------------
__global__ void k_finalize(const float* __restrict__ sums, const float* __restrict__ g,
                           const float* __restrict__ bt, float* __restrict__ s_out,
                           float* __restrict__ sh_out, float Nf) {
    int c = threadIdx.x;
    float mu = sums[c] / Nf;
    float var = sums[256 + c] / Nf - mu * mu;
    float rs = rsqrtf(var + BN_EPS);
    float sc = g[c] * rs;
    s_out[c] = sc;
    sh_out[c] = bt[c] - mu * sc;
}

// ---------------- global mean pool, two-stage (bf16 input) ----------------
__global__ void k_pool1(const unsigned short* __restrict__ h, const int* __restrict__ batch,
                        float* __restrict__ part, int N) {
    int g = blockIdx.x;
    int sidx = blockIdx.y;
    int c = threadIdx.x;   // 128
    int lo = 0, hi = N;
    while (lo < hi) { int m = (lo + hi) >> 1; if (batch[m] < g) lo = m + 1; else hi = m; }
    int start = lo; hi = N;
    while (lo < hi) { int m = (lo + hi) >> 1; if (batch[m] < g + 1) lo = m + 1; else hi = m; }
    int end = lo;
    float acc = 0.f;
    for (int r = start + sidx; r < end; r += POOL_S)
        acc += bf2f(h[(size_t)r * 128 + c]);
    part[((size_t)g * POOL_S + sidx) * 128 + c] = acc;
}

__global__ void k_pool2(const float* __restrict__ part, const int* __restrict__ batch,
                        const float* __restrict__ s, const float* __restrict__ sh,
                        float* __restrict__ out, int N) {
    int g = blockIdx.x;
    int c = threadIdx.x;   // 128
    int lo = 0, hi = N;
    while (lo < hi) { int m = (lo + hi) >> 1; if (batch[m] < g) lo = m + 1; else hi = m; }
    int start = lo; hi = N;
    while (lo < hi) { int m = (lo + hi) >> 1; if (batch[m] < g + 1) lo = m + 1; else hi = m; }
    int cnt = lo - start;
    float acc = 0.f;
    #pragma unroll
    for (int i = 0; i < POOL_S; ++i) acc += part[((size_t)g * POOL_S + i) * 128 + c];
    out[(size_t)g * 128 + c] = (cnt > 0) ? (s[c] * acc / (float)cnt + sh[c]) : 0.f;
}

// ---------------- host ----------------

static inline size_t align256(size_t x) { return (x + 255) & ~(size_t)255; }

extern "C" void kernel_launch(void* const* d_in, const int* in_sizes, int n_in,
                              void* d_out, int out_size, void* d_ws, size_t ws_size,
                              hipStream_t stream) {
    const float* x   = (const float*)d_in[0];
    const int* ei    = (const int*)d_in[1];
    const int* batch = (const int*)d_in[2];
    const float* Wp[4]  = {(const float*)d_in[3], (const float*)d_in[7],
                           (const float*)d_in[11], (const float*)d_in[15]};
    const float* bp[4]  = {(const float*)d_in[4], (const float*)d_in[8],
                           (const float*)d_in[12], (const float*)d_in[16]};
    const float* gp[4]  = {(const float*)d_in[5], (const float*)d_in[9],
                           (const float*)d_in[13], (const float*)d_in[17]};
    const float* btp[4] = {(const float*)d_in[6], (const float*)d_in[10],
                           (const float*)d_in[14], (const float*)d_in[18]};

    const int N = in_sizes[0] / 128;
    const int E = in_sizes[1] / 2;
    const int G = out_size / 128;

    char* p = (char*)d_ws;
    int* deg_cnt = (int*)p;            p += align256((size_t)N * 4);
    int* row_ptr = (int*)p;            p += align256((size_t)(N + 1) * 4);
    float* dinv = (float*)p;           p += align256((size_t)N * 4);
    float* self_norm = (float*)p;      p += align256((size_t)N * 4);
    int* csr_src = (int*)p;            p += align256((size_t)E * 4);
    float* csr_norm = (float*)p;       p += align256((size_t)E * 4);
    float* sums = (float*)p;           p += align256(512 * 4);
    float* s_arr = (float*)p;          p += align256(5 * 256 * 4);
    float* sh_arr = (float*)p;         p += align256(5 * 256 * 4);
    unsigned short* Wt = (unsigned short*)p; p += align256(256 * 256 * 2);
    float* part = (float*)p;           p += align256((size_t)G * POOL_S * 128 * 4);
    unsigned short* bufA = (unsigned short*)p; p += align256((size_t)N * 256 * 2);
    unsigned short* bufB = (unsigned short*)p; p += align256((size_t)N * 256 * 2);

    // ---- CSR build ----
    hipMemsetAsync(deg_cnt, 0, (size_t)N * 4, stream);
    k_count<<<(E + 255) / 256, 256, 0, stream>>>(ei, deg_cnt, E);
    k_deg<<<(N + 255) / 256, 256, 0, stream>>>(deg_cnt, dinv, self_norm, N);
    k_scan<<<1, 1024, 0, stream>>>(deg_cnt, row_ptr, N);
    hipMemsetAsync(deg_cnt, 0, (size_t)N * 4, stream);
    k_fill<<<(E + 255) / 256, 256, 0, stream>>>(ei, row_ptr, deg_cnt, dinv,
                                                csr_src, csr_norm, E);
    k_init_affine<<<1, 256, 0, stream>>>(s_arr, sh_arr);

    const int gblocks = (N + 127) / 128;

    for (int L = 0; L < 4; ++L) {
        const int di  = (L == 0) ? 128 : 256;
        const int doo = (L == 3) ? 128 : 256;
        if (L == 0)
            k_agg<128, false><<<N, 256, 0, stream>>>(x, s_arr, sh_arr,
                row_ptr, csr_src, csr_norm, self_norm, bufA);
        else
            k_agg<256, true><<<N, 256, 0, stream>>>(bufB, s_arr + L * 256, sh_arr + L * 256,
                row_ptr, csr_src, csr_norm, self_norm, bufA);
        k_prepW<<<(di * doo + 255) / 256, 256, 0, stream>>>(Wp[L], Wt, di, doo);
        hipMemsetAsync(sums, 0, 512 * 4, stream);
        if (L == 0)
            k_mfma<128, 256><<<gblocks, 1024, 0, stream>>>(bufA, Wt, bp[L], bufB, sums, N);
        else if (L == 3)
            k_mfma<256, 128><<<gblocks, 512, 0, stream>>>(bufA, Wt, bp[L], bufB, sums, N);
        else
            k_mfma<256, 256><<<gblocks, 1024, 0, stream>>>(bufA, Wt, bp[L], bufB, sums, N);
        k_finalize<<<1, doo, 0, stream>>>(sums, gp[L], btp[L],
                                          s_arr + (L + 1) * 256, sh_arr + (L + 1) * 256,
                                          (float)N);
    }

    dim3 pgrid(G, POOL_S);
    k_pool1<<<pgrid, 128, 0, stream>>>(bufB, batch, part, N);
    k_pool2<<<G, 128, 0, stream>>>(part, batch, s_arr + 4 * 256, sh_arr + 4 * 256,
                                   (float*)d_out, N);
}

// Round 4
// 696.860 us; speedup vs baseline: 2.3075x; 1.0108x over previous
//
#include <hip/hip_runtime.h>
#include <hip/hip_bf16.h>

#define NEG_SLOPE 0.01f
#define BN_EPS 1e-5f
#define POOL_S 16

typedef __attribute__((ext_vector_type(8))) short short8;
typedef __attribute__((ext_vector_type(4))) float f32x4;

struct alignas(8) Edge { int src; float w; };

__device__ __forceinline__ float bf2f(unsigned short b) {
    unsigned int u = ((unsigned int)b) << 16;
    float f; __builtin_memcpy(&f, &u, 4); return f;
}
__device__ __forceinline__ unsigned short f2bf(float f) {
    unsigned int u; __builtin_memcpy(&u, &f, 4);
    u = (u + 0x7FFFu + ((u >> 16) & 1u)) >> 16;
    return (unsigned short)u;
}

// ---------------- x fp32 -> bf16 ----------------
__global__ void k_cvt(const float* __restrict__ x, unsigned short* __restrict__ xb, int total8) {
    int i = blockIdx.x * blockDim.x + threadIdx.x;
    if (i < total8) {
        float4 a = ((const float4*)x)[i * 2];
        float4 b = ((const float4*)x)[i * 2 + 1];
        short8 o;
        o[0] = (short)f2bf(a.x); o[1] = (short)f2bf(a.y);
        o[2] = (short)f2bf(a.z); o[3] = (short)f2bf(a.w);
        o[4] = (short)f2bf(b.x); o[5] = (short)f2bf(b.y);
        o[6] = (short)f2bf(b.z); o[7] = (short)f2bf(b.w);
        ((short8*)xb)[i] = o;
    }
}

// ---------------- CSR build ----------------
__global__ void k_count(const int* __restrict__ ei, int* __restrict__ cnt, int E) {
    int e = blockIdx.x * blockDim.x + threadIdx.x;
    if (e < E) atomicAdd(&cnt[ei[E + e]], 1);
}

__global__ void k_deg(const int* __restrict__ cnt, float* __restrict__ dinv,
                      float* __restrict__ self_norm, int N) {
    int n = blockIdx.x * blockDim.x + threadIdx.x;
    if (n < N) {
        float deg = (float)(cnt[n] + 1);
        dinv[n] = rsqrtf(deg);
        self_norm[n] = 1.0f / deg;
    }
}

__global__ void k_scan(const int* __restrict__ cnt, int* __restrict__ row_ptr, int n) {
    __shared__ int wsum[16];
    __shared__ int carry_s;
    int tid = threadIdx.x;
    int lane = tid & 63, wid = tid >> 6;
    if (tid == 0) carry_s = 0;
    __syncthreads();
    for (int base = 0; base < n; base += 1024) {
        int i = base + tid;
        int v = (i < n) ? cnt[i] : 0;
        int x = v;
        #pragma unroll
        for (int off = 1; off < 64; off <<= 1) {
            int t = __shfl_up(x, off, 64);
            if (lane >= off) x += t;
        }
        if (lane == 63) wsum[wid] = x;
        __syncthreads();
        if (wid == 0 && lane < 16) {
            int s = wsum[lane];
            #pragma unroll
            for (int off = 1; off < 16; off <<= 1) {
                int t = __shfl_up(s, off, 16);
                if ((lane & 15) >= off) s += t;
            }
            wsum[lane] = s;
        }
        __syncthreads();
        int woff = (wid == 0) ? 0 : wsum[wid - 1];
        int incl = x + woff;
        if (i < n) row_ptr[i] = carry_s + incl - v;
        __syncthreads();
        if (tid == 0) carry_s += wsum[15];
        __syncthreads();
    }
    if (tid == 0) row_ptr[n] = carry_s;
}

__global__ void k_fill(const int* __restrict__ ei, const int* __restrict__ row_ptr,
                       int* __restrict__ fill, const float* __restrict__ dinv,
                       Edge* __restrict__ edges, int E) {
    int e = blockIdx.x * blockDim.x + threadIdx.x;
    if (e < E) {
        int src = ei[e];
        int dst = ei[E + e];
        int pos = atomicAdd(&fill[dst], 1);
        Edge ed; ed.src = src; ed.w = dinv[src] * dinv[dst];
        edges[row_ptr[dst] + pos] = ed;
    }
}

__global__ void k_init_affine(float* __restrict__ s, float* __restrict__ sh) {
    int c = threadIdx.x;
    s[c] = 1.0f;
    sh[c] = 0.0f;
}

// ---------------- W prep: Wt[n][k] = (scale?scale[k]:1) * W[k][n], bf16 ----------------
__global__ void k_prepW(const float* __restrict__ W, const float* __restrict__ scale,
                        unsigned short* __restrict__ Wt, int K, int DO) {
    int idx = blockIdx.x * blockDim.x + threadIdx.x;
    if (idx < K * DO) {
        int k = idx / DO, n = idx % DO;
        float v = W[idx];
        if (scale) v *= scale[k];
        Wt[(size_t)n * K + k] = f2bf(v);
    }
}

// d[c] = sum_k sh[k] * W[k][c]
__global__ void k_prepd(const float* __restrict__ W, const float* __restrict__ sh,
                        float* __restrict__ d, int K, int DO) {
    int c = blockIdx.x * blockDim.x + threadIdx.x;
    if (c < DO) {
        float a = 0.f;
        for (int k = 0; k < K; ++k) a += sh[k] * W[(size_t)k * DO + c];
        d[c] = a;
    }
}

// ---------------- wave-per-node aggregation ----------------
// non-EPI: t[n][c] = s[c]*(sum_e w*h[src][c] + sn*h[n][c]) + sh[c]*(sum_e w + sn)
// EPI:     t[n][c] = leaky(sum_e w*h[src][c] + sn*h[n][c] + ws*dv[c] + bias[c])
template<int COLS, bool EPI>
__global__ __launch_bounds__(256) void k_aggw(const unsigned short* __restrict__ h,
    const float* __restrict__ s, const float* __restrict__ sh,
    const float* __restrict__ dv, const float* __restrict__ bias,
    const int* __restrict__ row_ptr, const Edge* __restrict__ edges,
    const float* __restrict__ self_norm, unsigned short* __restrict__ t, int N) {
    constexpr int LPR = COLS / 8;       // lanes covering one row
    constexpr int GR  = 64 / LPR;       // edge-parallel groups per wave
    int n = blockIdx.x * 4 + (threadIdx.x >> 6);
    if (n >= N) return;
    int l = threadIdx.x & 63;
    int ct = l & (LPR - 1);
    int gp = l / LPR;
    int b = row_ptr[n], e = row_ptr[n + 1];
    float acc[8] = {};
    float wsum = 0.f;
    for (int j = b + gp; j < e; j += GR) {
        Edge ed = edges[j];
        short8 hv = *(const short8*)(h + (size_t)ed.src * COLS + ct * 8);
        #pragma unroll
        for (int i = 0; i < 8; ++i) acc[i] += ed.w * bf2f((unsigned short)hv[i]);
        wsum += ed.w;
    }
    #pragma unroll
    for (int mask = LPR; mask < 64; mask <<= 1) {
        #pragma unroll
        for (int i = 0; i < 8; ++i) acc[i] += __shfl_xor(acc[i], mask, 64);
        wsum += __shfl_xor(wsum, mask, 64);
    }
    if (gp == 0) {
        float sn = self_norm[n];
        float ws = wsum + sn;
        short8 hsv = *(const short8*)(h + (size_t)n * COLS + ct * 8);
        short8 ov;
        #pragma unroll
        for (int i = 0; i < 8; ++i) {
            int col = ct * 8 + i;
            float hv = bf2f((unsigned short)hsv[i]);
            float o;
            if constexpr (EPI) {
                o = acc[i] + sn * hv + ws * dv[col] + bias[col];
                o = o > 0.f ? o : NEG_SLOPE * o;
            } else {
                o = s[col] * (acc[i] + sn * hv) + sh[col] * ws;
            }
            ov[i] = (short)f2bf(o);
        }
        *(short8*)(t + (size_t)n * COLS + ct * 8) = ov;
    }
}

// ---------------- MFMA GEMM ----------------
// A: [M x K] bf16, Wt: [DO x K] bf16. FUSE: bias+leaky+bf16 store+BN partials. else plain bf16 store.
template<int K, int DO, bool FUSE>
__global__ __launch_bounds__(DO == 256 ? 1024 : 512) void k_mfma(
    const unsigned short* __restrict__ A, const unsigned short* __restrict__ Wt,
    const float* __restrict__ bias, unsigned short* __restrict__ H,
    float* __restrict__ sums, int M) {
    int tid = threadIdx.x;
    int l = tid & 63, w = tid >> 6;
    int wr = w & 1, wc = w >> 1;
    int Rb = blockIdx.x * 128 + wr * 64;
    int cb = wc * 32;
    int rl = l & 15;
    int kl = (l >> 4) * 8;
    f32x4 acc[4][2] = {};
    for (int k0 = 0; k0 < K; k0 += 32) {
        short8 b0 = *(const short8*)(Wt + (size_t)(cb + rl) * K + k0 + kl);
        short8 b1 = *(const short8*)(Wt + (size_t)(cb + 16 + rl) * K + k0 + kl);
        #pragma unroll
        for (int mf = 0; mf < 4; ++mf) {
            int row = Rb + mf * 16 + rl;
            if (row >= M) row = M - 1;
            short8 a = *(const short8*)(A + (size_t)row * K + k0 + kl);
            acc[mf][0] = __builtin_amdgcn_mfma_f32_16x16x32_bf16(a, b0, acc[mf][0], 0, 0, 0);
            acc[mf][1] = __builtin_amdgcn_mfma_f32_16x16x32_bf16(a, b1, acc[mf][1], 0, 0, 0);
        }
    }
    __shared__ float ls[2][DO];
    if constexpr (FUSE) {
        for (int c = tid; c < DO; c += blockDim.x) { ls[0][c] = 0.f; ls[1][c] = 0.f; }
        __syncthreads();
    }
    #pragma unroll
    for (int nf = 0; nf < 2; ++nf) {
        int col = cb + nf * 16 + rl;
        float bcol = FUSE ? bias[col] : 0.f;
        float p1 = 0.f, p2 = 0.f;
        #pragma unroll
        for (int mf = 0; mf < 4; ++mf) {
            #pragma unroll
            for (int r = 0; r < 4; ++r) {
                int row = Rb + mf * 16 + (l >> 4) * 4 + r;
                if (row < M) {
                    if constexpr (FUSE) {
                        float z = acc[mf][nf][r] + bcol;
                        z = z > 0.f ? z : NEG_SLOPE * z;
                        H[(size_t)row * DO + col] = f2bf(z);
                        p1 += z; p2 += z * z;
                    } else {
                        H[(size_t)row * DO + col] = f2bf(acc[mf][nf][r]);
                    }
                }
            }
        }
        if constexpr (FUSE) {
            atomicAdd(&ls[0][col], p1);
            atomicAdd(&ls[1][col], p2);
        }
    }
    if constexpr (FUSE) {
        __syncthreads();
        for (int c = tid; c < DO; c += blockDim.x) {
            atomicAdd(&sums[c], ls[0][c]);
            atomicAdd(&sums[256 + c], ls[1][c]);
        }
    }
}

// ---------------- BN stats over bf16 [M x 128] ----------------
__global__ void k_stats_bf(const unsigned short* __restrict__ h, float* __restrict__ sums, int M) {
    int c = threadIdx.x;   // 128
    float s1 = 0.f, s2 = 0.f;
    for (int r = blockIdx.x; r < M; r += gridDim.x) {
        float v = bf2f(h[(size_t)r * 128 + c]);
        s1 += v; s2 += v * v;
    }
    atomicAdd(&sums[c], s1);
    atomicAdd(&sums[256 + c], s2);
}

// ---------------- BN finalize -> affine ----------------
__global__ void k_finalize(const float* __restrict__ sums, const float* __restrict__ g,
                           const float* __restrict__ bt, float* __restrict__ s_out,
                           float* __restrict__ sh_out, float Nf) {
    int c = threadIdx.x;
    float mu = sums[c] / Nf;
    float var = sums[256 + c] / Nf - mu * mu;
    float rs = rsqrtf(var + BN_EPS);
    float sc = g[c] * rs;
    s_out[c] = sc;
    sh_out[c] = bt[c] - mu * sc;
}

// ---------------- global mean pool, two-stage ----------------
__global__ void k_pool1(const unsigned short* __restrict__ h, const int* __restrict__ batch,
                        float* __restrict__ part, int N) {
    int g = blockIdx.x;
    int sidx = blockIdx.y;
    int c = threadIdx.x;   // 128
    int lo = 0, hi = N;
    while (lo < hi) { int m = (lo + hi) >> 1; if (batch[m] < g) lo = m + 1; else hi = m; }
    int start = lo; hi = N;
    while (lo < hi) { int m = (lo + hi) >> 1; if (batch[m] < g + 1) lo = m + 1; else hi = m; }
    int end = lo;
    float acc = 0.f;
    for (int r = start + sidx; r < end; r += POOL_S)
        acc += bf2f(h[(size_t)r * 128 + c]);
    part[((size_t)g * POOL_S + sidx) * 128 + c] = acc;
}

__global__ void k_pool2(const float* __restrict__ part, const int* __restrict__ batch,
                        const float* __restrict__ s, const float* __restrict__ sh,
                        float* __restrict__ out, int N) {
    int g = blockIdx.x;
    int c = threadIdx.x;   // 128
    int lo = 0, hi = N;
    while (lo < hi) { int m = (lo + hi) >> 1; if (batch[m] < g) lo = m + 1; else hi = m; }
    int start = lo; hi = N;
    while (lo < hi) { int m = (lo + hi) >> 1; if (batch[m] < g + 1) lo = m + 1; else hi = m; }
    int cnt = lo - start;
    float acc = 0.f;
    #pragma unroll
    for (int i = 0; i < POOL_S; ++i) acc += part[((size_t)g * POOL_S + i) * 128 + c];
    out[(size_t)g * 128 + c] = (cnt > 0) ? (s[c] * acc / (float)cnt + sh[c]) : 0.f;
}

// ---------------- host ----------------

static inline size_t align256(size_t x) { return (x + 255) & ~(size_t)255; }

extern "C" void kernel_launch(void* const* d_in, const int* in_sizes, int n_in,
                              void* d_out, int out_size, void* d_ws, size_t ws_size,
                              hipStream_t stream) {
    const float* x   = (const float*)d_in[0];
    const int* ei    = (const int*)d_in[1];
    const int* batch = (const int*)d_in[2];
    const float* Wp[4]  = {(const float*)d_in[3], (const float*)d_in[7],
                           (const float*)d_in[11], (const float*)d_in[15]};
    const float* bp[4]  = {(const float*)d_in[4], (const float*)d_in[8],
                           (const float*)d_in[12], (const float*)d_in[16]};
    const float* gp[4]  = {(const float*)d_in[5], (const float*)d_in[9],
                           (const float*)d_in[13], (const float*)d_in[17]};
    const float* btp[4] = {(const float*)d_in[6], (const float*)d_in[10],
                           (const float*)d_in[14], (const float*)d_in[18]};

    const int N = in_sizes[0] / 128;
    const int E = in_sizes[1] / 2;
    const int G = out_size / 128;

    char* p = (char*)d_ws;
    int* deg_cnt = (int*)p;            p += align256((size_t)N * 4);
    int* row_ptr = (int*)p;            p += align256((size_t)(N + 1) * 4);
    float* dinv = (float*)p;           p += align256((size_t)N * 4);
    float* self_norm = (float*)p;      p += align256((size_t)N * 4);
    Edge* edges = (Edge*)p;            p += align256((size_t)E * 8);
    float* sums = (float*)p;           p += align256(512 * 4);
    float* s_arr = (float*)p;          p += align256(5 * 256 * 4);
    float* sh_arr = (float*)p;         p += align256(5 * 256 * 4);
    float* dvec = (float*)p;           p += align256(256 * 4);
    unsigned short* Wt = (unsigned short*)p; p += align256(256 * 256 * 2);
    float* part = (float*)p;           p += align256((size_t)G * POOL_S * 128 * 4);
    unsigned short* xb = (unsigned short*)p;   p += align256((size_t)N * 128 * 2);
    unsigned short* bufA = (unsigned short*)p; p += align256((size_t)N * 256 * 2);
    unsigned short* bufB = (unsigned short*)p; p += align256((size_t)N * 256 * 2);

    // x -> bf16
    k_cvt<<<(N * 128 / 8 + 255) / 256, 256, 0, stream>>>(x, xb, N * 128 / 8);

    // ---- CSR build ----
    hipMemsetAsync(deg_cnt, 0, (size_t)N * 4, stream);
    k_count<<<(E + 255) / 256, 256, 0, stream>>>(ei, deg_cnt, E);
    k_deg<<<(N + 255) / 256, 256, 0, stream>>>(deg_cnt, dinv, self_norm, N);
    k_scan<<<1, 1024, 0, stream>>>(deg_cnt, row_ptr, N);
    hipMemsetAsync(deg_cnt, 0, (size_t)N * 4, stream);
    k_fill<<<(E + 255) / 256, 256, 0, stream>>>(ei, row_ptr, deg_cnt, dinv, edges, E);
    k_init_affine<<<1, 256, 0, stream>>>(s_arr, sh_arr);

    const int ablocks = (N + 3) / 4;
    const int gblocks = (N + 127) / 128;

    // ---- L1: agg(xb) -> bufA [N,128]; mfma 128->256 fused -> bufB ----
    k_aggw<128, false><<<ablocks, 256, 0, stream>>>(xb, s_arr, sh_arr, nullptr, nullptr,
        row_ptr, edges, self_norm, bufA, N);
    k_prepW<<<(128 * 256 + 255) / 256, 256, 0, stream>>>(Wp[0], nullptr, Wt, 128, 256);
    hipMemsetAsync(sums, 0, 512 * 4, stream);
    k_mfma<128, 256, true><<<gblocks, 1024, 0, stream>>>(bufA, Wt, bp[0], bufB, sums, N);
    k_finalize<<<1, 256, 0, stream>>>(sums, gp[0], btp[0], s_arr + 256, sh_arr + 256, (float)N);

    // ---- L2, L3 ----
    for (int L = 1; L <= 2; ++L) {
        k_aggw<256, false><<<ablocks, 256, 0, stream>>>(bufB, s_arr + L * 256, sh_arr + L * 256,
            nullptr, nullptr, row_ptr, edges, self_norm, bufA, N);
        k_prepW<<<(256 * 256 + 255) / 256, 256, 0, stream>>>(Wp[L], nullptr, Wt, 256, 256);
        hipMemsetAsync(sums, 0, 512 * 4, stream);
        k_mfma<256, 256, true><<<gblocks, 1024, 0, stream>>>(bufA, Wt, bp[L], bufB, sums, N);
        k_finalize<<<1, 256, 0, stream>>>(sums, gp[L], btp[L],
                                          s_arr + (L + 1) * 256, sh_arr + (L + 1) * 256, (float)N);
    }

    // ---- L4: GEMM-first (fold s4 into W, sh4 into dvec), then agg in 128 cols ----
    k_prepW<<<(256 * 128 + 255) / 256, 256, 0, stream>>>(Wp[3], s_arr + 3 * 256, Wt, 256, 128);
    k_prepd<<<1, 128, 0, stream>>>(Wp[3], sh_arr + 3 * 256, dvec, 256, 128);
    k_mfma<256, 128, false><<<gblocks, 512, 0, stream>>>(bufB, Wt, nullptr, bufA, nullptr, N);
    k_aggw<128, true><<<ablocks, 256, 0, stream>>>(bufA, nullptr, nullptr, dvec, bp[3],
        row_ptr, edges, self_norm, bufB, N);
    hipMemsetAsync(sums, 0, 512 * 4, stream);
    k_stats_bf<<<256, 128, 0, stream>>>(bufB, sums, N);
    k_finalize<<<1, 128, 0, stream>>>(sums, gp[3], btp[3], s_arr + 4 * 256, sh_arr + 4 * 256, (float)N);

    // ---- pool ----
    dim3 pgrid(G, POOL_S);
    k_pool1<<<pgrid, 128, 0, stream>>>(bufB, batch, part, N);
    k_pool2<<<G, 128, 0, stream>>>(part, batch, s_arr + 4 * 256, sh_arr + 4 * 256,
                                   (float*)d_out, N);
}

// Round 5
// 625.067 us; speedup vs baseline: 2.5726x; 1.1149x over previous
//
#include <hip/hip_runtime.h>
#include <hip/hip_bf16.h>

#define NEG_SLOPE 0.01f
#define BN_EPS 1e-5f
#define POOL_S 16

typedef __attribute__((ext_vector_type(8))) short short8;
typedef __attribute__((ext_vector_type(4))) float f32x4;

struct alignas(8) Edge { int src; float w; };

__device__ __forceinline__ float bf2f(unsigned short b) {
    unsigned int u = ((unsigned int)b) << 16;
    float f; __builtin_memcpy(&f, &u, 4); return f;
}
__device__ __forceinline__ unsigned short f2bf(float f) {
    unsigned int u; __builtin_memcpy(&u, &f, 4);
    u = (u + 0x7FFFu + ((u >> 16) & 1u)) >> 16;
    return (unsigned short)u;
}

__device__ __forceinline__ void gload_lds16(const void* g, void* l) {
    __builtin_amdgcn_global_load_lds(
        (const __attribute__((address_space(1))) void*)g,
        (__attribute__((address_space(3))) void*)l, 16, 0, 0);
}

// ---------------- x fp32 -> bf16 ----------------
__global__ void k_cvt(const float* __restrict__ x, unsigned short* __restrict__ xb, int total8) {
    int i = blockIdx.x * blockDim.x + threadIdx.x;
    if (i < total8) {
        float4 a = ((const float4*)x)[i * 2];
        float4 b = ((const float4*)x)[i * 2 + 1];
        short8 o;
        o[0] = (short)f2bf(a.x); o[1] = (short)f2bf(a.y);
        o[2] = (short)f2bf(a.z); o[3] = (short)f2bf(a.w);
        o[4] = (short)f2bf(b.x); o[5] = (short)f2bf(b.y);
        o[6] = (short)f2bf(b.z); o[7] = (short)f2bf(b.w);
        ((short8*)xb)[i] = o;
    }
}

// ---------------- CSR build ----------------
__global__ void k_count(const int* __restrict__ ei, int* __restrict__ cnt, int E) {
    int e = blockIdx.x * blockDim.x + threadIdx.x;
    if (e < E) atomicAdd(&cnt[ei[E + e]], 1);
}

__global__ void k_deg(const int* __restrict__ cnt, float* __restrict__ dinv,
                      float* __restrict__ self_norm, int N) {
    int n = blockIdx.x * blockDim.x + threadIdx.x;
    if (n < N) {
        float deg = (float)(cnt[n] + 1);
        dinv[n] = rsqrtf(deg);
        self_norm[n] = 1.0f / deg;
    }
}

__global__ void k_scan(const int* __restrict__ cnt, int* __restrict__ row_ptr, int n) {
    __shared__ int wsum[16];
    __shared__ int carry_s;
    int tid = threadIdx.x;
    int lane = tid & 63, wid = tid >> 6;
    if (tid == 0) carry_s = 0;
    __syncthreads();
    for (int base = 0; base < n; base += 1024) {
        int i = base + tid;
        int v = (i < n) ? cnt[i] : 0;
        int x = v;
        #pragma unroll
        for (int off = 1; off < 64; off <<= 1) {
            int t = __shfl_up(x, off, 64);
            if (lane >= off) x += t;
        }
        if (lane == 63) wsum[wid] = x;
        __syncthreads();
        if (wid == 0 && lane < 16) {
            int s = wsum[lane];
            #pragma unroll
            for (int off = 1; off < 16; off <<= 1) {
                int t = __shfl_up(s, off, 16);
                if ((lane & 15) >= off) s += t;
            }
            wsum[lane] = s;
        }
        __syncthreads();
        int woff = (wid == 0) ? 0 : wsum[wid - 1];
        int incl = x + woff;
        if (i < n) row_ptr[i] = carry_s + incl - v;
        __syncthreads();
        if (tid == 0) carry_s += wsum[15];
        __syncthreads();
    }
    if (tid == 0) row_ptr[n] = carry_s;
}

__global__ void k_fill(const int* __restrict__ ei, const int* __restrict__ row_ptr,
                       int* __restrict__ fill, const float* __restrict__ dinv,
                       Edge* __restrict__ edges, int E) {
    int e = blockIdx.x * blockDim.x + threadIdx.x;
    if (e < E) {
        int src = ei[e];
        int dst = ei[E + e];
        int pos = atomicAdd(&fill[dst], 1);
        Edge ed; ed.src = src; ed.w = dinv[src] * dinv[dst];
        edges[row_ptr[dst] + pos] = ed;
    }
}

__global__ void k_init_affine(float* __restrict__ s, float* __restrict__ sh) {
    int c = threadIdx.x;
    s[c] = 1.0f;
    sh[c] = 0.0f;
}

// ---------------- W prep: Wt[n][k] = (scale?scale[k]:1) * W[k][n], bf16 ----------------
__global__ void k_prepW(const float* __restrict__ W, const float* __restrict__ scale,
                        unsigned short* __restrict__ Wt, int K, int DO) {
    int idx = blockIdx.x * blockDim.x + threadIdx.x;
    if (idx < K * DO) {
        int k = idx / DO, n = idx % DO;
        float v = W[idx];
        if (scale) v *= scale[k];
        Wt[(size_t)n * K + k] = f2bf(v);
    }
}

// d[c] = sum_k sh[k] * W[k][c]
__global__ void k_prepd(const float* __restrict__ W, const float* __restrict__ sh,
                        float* __restrict__ d, int K, int DO) {
    int c = blockIdx.x * blockDim.x + threadIdx.x;
    if (c < DO) {
        float a = 0.f;
        for (int k = 0; k < K; ++k) a += sh[k] * W[(size_t)k * DO + c];
        d[c] = a;
    }
}

// ---------------- wave-per-node aggregation ----------------
template<int COLS, bool EPI>
__global__ __launch_bounds__(256) void k_aggw(const unsigned short* __restrict__ h,
    const float* __restrict__ s, const float* __restrict__ sh,
    const float* __restrict__ dv, const float* __restrict__ bias,
    const int* __restrict__ row_ptr, const Edge* __restrict__ edges,
    const float* __restrict__ self_norm, unsigned short* __restrict__ t, int N) {
    constexpr int LPR = COLS / 8;
    constexpr int GR  = 64 / LPR;
    int n = blockIdx.x * 4 + (threadIdx.x >> 6);
    if (n >= N) return;
    int l = threadIdx.x & 63;
    int ct = l & (LPR - 1);
    int gp = l / LPR;
    int b = row_ptr[n], e = row_ptr[n + 1];
    float acc[8] = {};
    float wsum = 0.f;
    for (int j = b + gp; j < e; j += GR) {
        Edge ed = edges[j];
        short8 hv = *(const short8*)(h + (size_t)ed.src * COLS + ct * 8);
        #pragma unroll
        for (int i = 0; i < 8; ++i) acc[i] += ed.w * bf2f((unsigned short)hv[i]);
        wsum += ed.w;
    }
    #pragma unroll
    for (int mask = LPR; mask < 64; mask <<= 1) {
        #pragma unroll
        for (int i = 0; i < 8; ++i) acc[i] += __shfl_xor(acc[i], mask, 64);
        wsum += __shfl_xor(wsum, mask, 64);
    }
    if (gp == 0) {
        float sn = self_norm[n];
        float ws = wsum + sn;
        short8 hsv = *(const short8*)(h + (size_t)n * COLS + ct * 8);
        short8 ov;
        #pragma unroll
        for (int i = 0; i < 8; ++i) {
            int col = ct * 8 + i;
            float hv = bf2f((unsigned short)hsv[i]);
            float o;
            if constexpr (EPI) {
                o = acc[i] + sn * hv + ws * dv[col] + bias[col];
                o = o > 0.f ? o : NEG_SLOPE * o;
            } else {
                o = s[col] * (acc[i] + sn * hv) + sh[col] * ws;
            }
            ov[i] = (short)f2bf(o);
        }
        *(short8*)(t + (size_t)n * COLS + ct * 8) = ov;
    }
}

// ---------------- staged MFMA GEMM ----------------
// A: [M x K] bf16, Wt: [DO x K] bf16. Tile 128x128, BK=64, 4 waves.
// LDS tiles [128 rows][8 slots of 16B], slot XOR-swizzled by (row&7).
// global_load_lds writes linearly -> inverse-swizzle the global SOURCE (rule 21).
template<int K, int DO, bool FUSE>
__global__ __launch_bounds__(256) void k_mfma2(
    const unsigned short* __restrict__ A, const unsigned short* __restrict__ Wt,
    const float* __restrict__ bias, unsigned short* __restrict__ H,
    float* __restrict__ sums, int M) {
    __shared__ unsigned short Asm[128 * 64];
    __shared__ unsigned short Bsm[128 * 64];
    __shared__ float ls[2][128];
    int tid = threadIdx.x;
    int l = tid & 63, w = tid >> 6;
    int wr = w & 1, wc = w >> 1;           // 2x2 wave grid
    int rl = l & 15, kh = l >> 4;          // fragment lane decomposition
    int Rb = blockIdx.x * 128;
    int Cb = blockIdx.y * 128;
    // staging indices (same for A and B)
    int srow = tid >> 3;                   // 0..31 within 32-row chunk
    int sd   = tid & 7;                    // dest 16B slot
    f32x4 acc[4][4] = {};
    for (int k0 = 0; k0 < K; k0 += 64) {
        #pragma unroll
        for (int i = 0; i < 4; ++i) {
            int row = i * 32 + srow;
            int ss = sd ^ (row & 7);       // inverse-swizzled source slot
            int rg = Rb + row; if (rg >= M) rg = M - 1;
            gload_lds16(A + (size_t)rg * K + k0 + ss * 8,
                        (char*)Asm + i * 4096 + w * 1024);
            gload_lds16(Wt + (size_t)(Cb + row) * K + k0 + ss * 8,
                        (char*)Bsm + i * 4096 + w * 1024);
        }
        __syncthreads();
        #pragma unroll
        for (int kk = 0; kk < 2; ++kk) {
            short8 af[4], bf[4];
            #pragma unroll
            for (int mf = 0; mf < 4; ++mf) {
                int r = wr * 64 + mf * 16 + rl;
                int slot = (kk * 4 + kh) ^ (r & 7);
                af[mf] = *(const short8*)((const char*)Asm + r * 128 + slot * 16);
            }
            #pragma unroll
            for (int nf = 0; nf < 4; ++nf) {
                int c = wc * 64 + nf * 16 + rl;
                int slot = (kk * 4 + kh) ^ (c & 7);
                bf[nf] = *(const short8*)((const char*)Bsm + c * 128 + slot * 16);
            }
            #pragma unroll
            for (int mf = 0; mf < 4; ++mf)
                #pragma unroll
                for (int nf = 0; nf < 4; ++nf)
                    acc[mf][nf] = __builtin_amdgcn_mfma_f32_16x16x32_bf16(
                        af[mf], bf[nf], acc[mf][nf], 0, 0, 0);
        }
        __syncthreads();
    }
    if constexpr (FUSE) {
        for (int c = tid; c < 128; c += 256) { ls[0][c] = 0.f; ls[1][c] = 0.f; }
        __syncthreads();
    }
    #pragma unroll
    for (int nf = 0; nf < 4; ++nf) {
        int cl = wc * 64 + nf * 16 + rl;
        int col = Cb + cl;
        float bcol = FUSE ? bias[col] : 0.f;
        float p1 = 0.f, p2 = 0.f;
        #pragma unroll
        for (int mf = 0; mf < 4; ++mf) {
            #pragma unroll
            for (int r = 0; r < 4; ++r) {
                int row = Rb + wr * 64 + mf * 16 + kh * 4 + r;
                if (row < M) {
                    if constexpr (FUSE) {
                        float z = acc[mf][nf][r] + bcol;
                        z = z > 0.f ? z : NEG_SLOPE * z;
                        H[(size_t)row * DO + col] = f2bf(z);
                        p1 += z; p2 += z * z;
                    } else {
                        H[(size_t)row * DO + col] = f2bf(acc[mf][nf][r]);
                    }
                }
            }
        }
        if constexpr (FUSE) {
            atomicAdd(&ls[0][cl], p1);
            atomicAdd(&ls[1][cl], p2);
        }
    }
    if constexpr (FUSE) {
        __syncthreads();
        for (int c = tid; c < 128; c += 256) {
            atomicAdd(&sums[Cb + c], ls[0][c]);
            atomicAdd(&sums[256 + Cb + c], ls[1][c]);
        }
    }
}

// ---------------- BN stats over bf16 [M x 128] ----------------
__global__ void k_stats_bf(const unsigned short* __restrict__ h, float* __restrict__ sums, int M) {
    int c = threadIdx.x;
    float s1 = 0.f, s2 = 0.f;
    for (int r = blockIdx.x; r < M; r += gridDim.x) {
        float v = bf2f(h[(size_t)r * 128 + c]);
        s1 += v; s2 += v * v;
    }
    atomicAdd(&sums[c], s1);
    atomicAdd(&sums[256 + c], s2);
}

// ---------------- BN finalize -> affine ----------------
__global__ void k_finalize(const float* __restrict__ sums, const float* __restrict__ g,
                           const float* __restrict__ bt, float* __restrict__ s_out,
                           float* __restrict__ sh_out, float Nf) {
    int c = threadIdx.x;
    float mu = sums[c] / Nf;
    float var = sums[256 + c] / Nf - mu * mu;
    float rs = rsqrtf(var + BN_EPS);
    float sc = g[c] * rs;
    s_out[c] = sc;
    sh_out[c] = bt[c] - mu * sc;
}

// ---------------- global mean pool, two-stage ----------------
__global__ void k_pool1(const unsigned short* __restrict__ h, const int* __restrict__ batch,
                        float* __restrict__ part, int N) {
    int g = blockIdx.x;
    int sidx = blockIdx.y;
    int c = threadIdx.x;
    int lo = 0, hi = N;
    while (lo < hi) { int m = (lo + hi) >> 1; if (batch[m] < g) lo = m + 1; else hi = m; }
    int start = lo; hi = N;
    while (lo < hi) { int m = (lo + hi) >> 1; if (batch[m] < g + 1) lo = m + 1; else hi = m; }
    int end = lo;
    float acc = 0.f;
    for (int r = start + sidx; r < end; r += POOL_S)
        acc += bf2f(h[(size_t)r * 128 + c]);
    part[((size_t)g * POOL_S + sidx) * 128 + c] = acc;
}

__global__ void k_pool2(const float* __restrict__ part, const int* __restrict__ batch,
                        const float* __restrict__ s, const float* __restrict__ sh,
                        float* __restrict__ out, int N) {
    int g = blockIdx.x;
    int c = threadIdx.x;
    int lo = 0, hi = N;
    while (lo < hi) { int m = (lo + hi) >> 1; if (batch[m] < g) lo = m + 1; else hi = m; }
    int start = lo; hi = N;
    while (lo < hi) { int m = (lo + hi) >> 1; if (batch[m] < g + 1) lo = m + 1; else hi = m; }
    int cnt = lo - start;
    float acc = 0.f;
    #pragma unroll
    for (int i = 0; i < POOL_S; ++i) acc += part[((size_t)g * POOL_S + i) * 128 + c];
    out[(size_t)g * 128 + c] = (cnt > 0) ? (s[c] * acc / (float)cnt + sh[c]) : 0.f;
}

// ---------------- host ----------------

static inline size_t align256(size_t x) { return (x + 255) & ~(size_t)255; }

extern "C" void kernel_launch(void* const* d_in, const int* in_sizes, int n_in,
                              void* d_out, int out_size, void* d_ws, size_t ws_size,
                              hipStream_t stream) {
    const float* x   = (const float*)d_in[0];
    const int* ei    = (const int*)d_in[1];
    const int* batch = (const int*)d_in[2];
    const float* Wp[4]  = {(const float*)d_in[3], (const float*)d_in[7],
                           (const float*)d_in[11], (const float*)d_in[15]};
    const float* bp[4]  = {(const float*)d_in[4], (const float*)d_in[8],
                           (const float*)d_in[12], (const float*)d_in[16]};
    const float* gp[4]  = {(const float*)d_in[5], (const float*)d_in[9],
                           (const float*)d_in[13], (const float*)d_in[17]};
    const float* btp[4] = {(const float*)d_in[6], (const float*)d_in[10],
                           (const float*)d_in[14], (const float*)d_in[18]};

    const int N = in_sizes[0] / 128;
    const int E = in_sizes[1] / 2;
    const int G = out_size / 128;

    char* p = (char*)d_ws;
    int* deg_cnt = (int*)p;            p += align256((size_t)N * 4);
    int* row_ptr = (int*)p;            p += align256((size_t)(N + 1) * 4);
    float* dinv = (float*)p;           p += align256((size_t)N * 4);
    float* self_norm = (float*)p;      p += align256((size_t)N * 4);
    Edge* edges = (Edge*)p;            p += align256((size_t)E * 8);
    float* sums = (float*)p;           p += align256(512 * 4);
    float* s_arr = (float*)p;          p += align256(5 * 256 * 4);
    float* sh_arr = (float*)p;         p += align256(5 * 256 * 4);
    float* dvec = (float*)p;           p += align256(256 * 4);
    unsigned short* Wt = (unsigned short*)p; p += align256(256 * 256 * 2);
    float* part = (float*)p;           p += align256((size_t)G * POOL_S * 128 * 4);
    unsigned short* xb = (unsigned short*)p;   p += align256((size_t)N * 128 * 2);
    unsigned short* bufA = (unsigned short*)p; p += align256((size_t)N * 256 * 2);
    unsigned short* bufB = (unsigned short*)p; p += align256((size_t)N * 256 * 2);

    k_cvt<<<(N * 128 / 8 + 255) / 256, 256, 0, stream>>>(x, xb, N * 128 / 8);

    hipMemsetAsync(deg_cnt, 0, (size_t)N * 4, stream);
    k_count<<<(E + 255) / 256, 256, 0, stream>>>(ei, deg_cnt, E);
    k_deg<<<(N + 255) / 256, 256, 0, stream>>>(deg_cnt, dinv, self_norm, N);
    k_scan<<<1, 1024, 0, stream>>>(deg_cnt, row_ptr, N);
    hipMemsetAsync(deg_cnt, 0, (size_t)N * 4, stream);
    k_fill<<<(E + 255) / 256, 256, 0, stream>>>(ei, row_ptr, deg_cnt, dinv, edges, E);
    k_init_affine<<<1, 256, 0, stream>>>(s_arr, sh_arr);

    const int ablocks = (N + 3) / 4;
    const int gx = (N + 127) / 128;

    // ---- L1: agg(xb) [N,128] -> mfma 128->256 fused ----
    k_aggw<128, false><<<ablocks, 256, 0, stream>>>(xb, s_arr, sh_arr, nullptr, nullptr,
        row_ptr, edges, self_norm, bufA, N);
    k_prepW<<<(128 * 256 + 255) / 256, 256, 0, stream>>>(Wp[0], nullptr, Wt, 128, 256);
    hipMemsetAsync(sums, 0, 512 * 4, stream);
    k_mfma2<128, 256, true><<<dim3(gx, 2), 256, 0, stream>>>(bufA, Wt, bp[0], bufB, sums, N);
    k_finalize<<<1, 256, 0, stream>>>(sums, gp[0], btp[0], s_arr + 256, sh_arr + 256, (float)N);

    // ---- L2, L3 ----
    for (int L = 1; L <= 2; ++L) {
        k_aggw<256, false><<<ablocks, 256, 0, stream>>>(bufB, s_arr + L * 256, sh_arr + L * 256,
            nullptr, nullptr, row_ptr, edges, self_norm, bufA, N);
        k_prepW<<<(256 * 256 + 255) / 256, 256, 0, stream>>>(Wp[L], nullptr, Wt, 256, 256);
        hipMemsetAsync(sums, 0, 512 * 4, stream);
        k_mfma2<256, 256, true><<<dim3(gx, 2), 256, 0, stream>>>(bufA, Wt, bp[L], bufB, sums, N);
        k_finalize<<<1, 256, 0, stream>>>(sums, gp[L], btp[L],
                                          s_arr + (L + 1) * 256, sh_arr + (L + 1) * 256, (float)N);
    }

    // ---- L4: GEMM-first (fold s4 into W, sh4 into dvec), then agg in 128 cols ----
    k_prepW<<<(256 * 128 + 255) / 256, 256, 0, stream>>>(Wp[3], s_arr + 3 * 256, Wt, 256, 128);
    k_prepd<<<1, 128, 0, stream>>>(Wp[3], sh_arr + 3 * 256, dvec, 256, 128);
    k_mfma2<256, 128, false><<<dim3(gx, 1), 256, 0, stream>>>(bufB, Wt, nullptr, bufA, nullptr, N);
    k_aggw<128, true><<<ablocks, 256, 0, stream>>>(bufA, nullptr, nullptr, dvec, bp[3],
        row_ptr, edges, self_norm, bufB, N);
    hipMemsetAsync(sums, 0, 512 * 4, stream);
    k_stats_bf<<<256, 128, 0, stream>>>(bufB, sums, N);
    k_finalize<<<1, 128, 0, stream>>>(sums, gp[3], btp[3], s_arr + 4 * 256, sh_arr + 4 * 256, (float)N);

    dim3 pgrid(G, POOL_S);
    k_pool1<<<pgrid, 128, 0, stream>>>(bufB, batch, part, N);
    k_pool2<<<G, 128, 0, stream>>>(part, batch, s_arr + 4 * 256, sh_arr + 4 * 256,
                                   (float*)d_out, N);
}